// Round 1
// baseline (90.530 us; speedup 1.0000x reference)
//
#include <hip/hip_runtime.h>

typedef float  float4_t __attribute__((ext_vector_type(4)));
typedef int    int4_t   __attribute__((ext_vector_type(4)));

// One fused elementwise kernel over vec4 work-units:
//   units [0, nv4)            : new_vals = keep ? vals/kr : 0
//   units [nv4, nv4 + ni4)    : out[E + j] = (float)idxs[j]   (pass-through, cast to f32
//                               because d_out is a float buffer per harness contract)
__global__ void SpAdjDropEdge_48541720379660_kernel(
    const float* __restrict__ vals,
    const int*   __restrict__ idxs,
    const float* __restrict__ rand_u,
    const float* __restrict__ keep_rate_p,
    float*       __restrict__ out,
    int nv4, int ni4)
{
    const float kr = keep_rate_p[0];
    const int total  = nv4 + ni4;
    const int stride = gridDim.x * blockDim.x;

    for (int i = blockIdx.x * blockDim.x + threadIdx.x; i < total; i += stride) {
        if (i < nv4) {
            float4_t v = reinterpret_cast<const float4_t*>(vals)[i];
            float4_t r = reinterpret_cast<const float4_t*>(rand_u)[i];
            float4_t o;
#pragma unroll
            for (int j = 0; j < 4; ++j) {
                // reference: mask = floor(rand_u + keep_rate) != 0
                bool keep = (floorf(r[j] + kr) != 0.0f);
                o[j] = keep ? (v[j] / kr) : 0.0f;
            }
            reinterpret_cast<float4_t*>(out)[i] = o;
        } else {
            const int k = i - nv4;
            int4_t id = reinterpret_cast<const int4_t*>(idxs)[k];
            float4_t o;
#pragma unroll
            for (int j = 0; j < 4; ++j) {
                o[j] = (float)id[j];   // node ids < 2^24 -> exact in f32
            }
            reinterpret_cast<float4_t*>(out + (size_t)nv4 * 4)[k] = o;
        }
    }
}

extern "C" void kernel_launch(void* const* d_in, const int* in_sizes, int n_in,
                              void* d_out, int out_size, void* d_ws, size_t ws_size,
                              hipStream_t stream)
{
    const float* vals   = (const float*)d_in[0];
    const int*   idxs   = (const int*)  d_in[1];
    const float* rand_u = (const float*)d_in[2];
    const float* kr     = (const float*)d_in[3];
    float*       out    = (float*)d_out;

    const int E  = in_sizes[0];       // 16,000,000
    const int NI = in_sizes[1];       // 2*E = 32,000,000
    const int nv4 = E  / 4;           // divisible by 4
    const int ni4 = NI / 4;

    const int block = 256;
    // ~2048-4096 blocks + grid-stride: enough waves to saturate HBM,
    // minimal launch/scheduling overhead (Guideline 11).
    const int grid  = 4096;

    SpAdjDropEdge_48541720379660_kernel<<<grid, block, 0, stream>>>(
        vals, idxs, rand_u, kr, out, nv4, ni4);
}